// Round 4
// baseline (439.781 us; speedup 1.0000x reference)
//
#include <hip/hip_runtime.h>
#include <hip/hip_bf16.h>
#include <hip/hip_fp16.h>
#include <cstdint>
#include <cstddef>

// Problem constants
#define B_ 4
#define K_ 8192
#define D_ 1024
#define M_ (B_*K_)      // 32768 rows in the GEMM
#define BD_ (B_*D_)     // 4096 scan chains

// Scan chunking: 512 chunks of 16 timesteps
#define CCH 512
#define LCH (K_/CCH)    // 16

// GEMM tiling
#define NTK 32          // K-tiles of 32 (D_/32)

typedef __bf16    bf16x8 __attribute__((ext_vector_type(8)));
typedef float     f32x4  __attribute__((ext_vector_type(4)));
typedef _Float16  f16x4  __attribute__((ext_vector_type(4)));

typedef __attribute__((address_space(1))) void as1void;
typedef __attribute__((address_space(3))) void as3void;

__device__ __forceinline__ void gload_lds16(const void* g, void* l) {
  // 16B-wide async global->LDS. LDS dest is wave-uniform base + lane*16.
  __builtin_amdgcn_global_load_lds((as1void*)g, (as3void*)l, 16, 0, 0);
}

__device__ __forceinline__ unsigned short f2bf_rne(float f) {
  unsigned u = __builtin_bit_cast(unsigned, f);
  u += 0x7fffu + ((u >> 16) & 1u);   // round-to-nearest-even
  return (unsigned short)(u >> 16);
}

// ---------------------------------------------------------------- convert ---
__global__ __launch_bounds__(256) void cvt_f32_to_bf16(
    const float* __restrict__ in, unsigned short* __restrict__ out, int n4) {
  int stride = gridDim.x * blockDim.x;
  for (int i = blockIdx.x * blockDim.x + threadIdx.x; i < n4; i += stride) {
    float4 v = reinterpret_cast<const float4*>(in)[i];
    ushort4 o;
    o.x = f2bf_rne(v.x); o.y = f2bf_rne(v.y);
    o.z = f2bf_rne(v.z); o.w = f2bf_rne(v.w);
    reinterpret_cast<ushort4*>(out)[i] = o;
  }
}

// ------------------------------------------------------------------- GEMM ---
// lam[m,e] = sigmoid( sum_d x[m,d]*W[e,d] + bias[e] ), stored fp16.
// 256x256 tile, BK=32, 8 waves (2Mx4N), 4 LDS buffers, 3-ahead prefetch,
// counted vmcnt(8) (never drained in loop), raw s_barrier, conflict-free
// k-group-major LDS layout via pre-permuted global source addresses.
__global__ __launch_bounds__(512, 2) void gemm_bias_sigmoid(
    const unsigned short* __restrict__ A,
    const unsigned short* __restrict__ Bw,
    const float* __restrict__ bias,
    _Float16* __restrict__ lamh) {
  extern __shared__ __attribute__((aligned(16))) unsigned short lds[];
  // Layout: buffer b (0..3) at b*16384 shorts; A tile [0,8192), B tile [8192,16384).
  // Within a tile: col8-group g (0..3), row r (0..255): short idx = g*2048 + r*8.

  const int t    = threadIdx.x;
  const int wave = t >> 6;
  const int lane = t & 63;
  const int wm   = wave >> 2;       // 0..1 : M-half (128 rows)
  const int wn   = wave & 3;        // 0..3 : N-quarter (64 cols)

  // XCD-chunked swizzle: 512 blocks; make the 4 col-blocks sharing an
  // A-panel land on the same XCD (b%8). Bijective: b = (r%8) + 8*((r/8)*4+c).
  const int b     = blockIdx.x;
  const int xcd   = b & 7;
  const int inner = b >> 3;
  const int cblk  = inner & 3;
  const int rblk  = (inner >> 2) * 8 + xcd;   // 0..127
  const int m0    = rblk * 256;
  const int n0    = cblk * 256;

  f32x4 acc[8][4] = {};

  const int sg  = wave & 3;          // staging col8-group for this wave
  const int rc0 = (wave >> 2) * 2;   // staging row-chunk base

  auto STAGE = [&](int buf, int kt) {
#pragma unroll
    for (int i = 0; i < 2; ++i) {
      const int rc = rc0 + i;
      unsigned short* la = &lds[buf * 16384 + sg * 2048 + (rc * 64 + lane) * 8];
      const unsigned short* ga = A + (size_t)(m0 + rc * 64 + lane) * D_ + kt + sg * 8;
      gload_lds16(ga, la);
      unsigned short* lb = la + 8192;
      const unsigned short* gb = Bw + (size_t)(n0 + rc * 64 + lane) * D_ + kt + sg * 8;
      gload_lds16(gb, lb);
    }
  };

  // fragment lane offsets (shorts): lane l reads rows (.. + l&15), k-group l>>4
  const int rl = lane & 15, kg = lane >> 4;
  const int aoff = kg * 2048 + rl * 8 + wm * 1024;          // + mf*128
  const int boff = kg * 2048 + rl * 8 + wn * 512 + 8192;    // + nf*128

  STAGE(0, 0); STAGE(1, 32); STAGE(2, 64);   // 12 loads/thread outstanding

  for (int tt = 0; tt < NTK; ++tt) {
    if (tt < NTK - 2)       asm volatile("s_waitcnt vmcnt(8)" ::: "memory");
    else if (tt == NTK - 2) asm volatile("s_waitcnt vmcnt(4)" ::: "memory");
    else                    asm volatile("s_waitcnt vmcnt(0)" ::: "memory");
    __builtin_amdgcn_s_barrier();
    asm volatile("" ::: "memory");
    if (tt + 3 < NTK) STAGE((tt + 3) & 3, (tt + 3) * 32);  // != current buffer
    const int base = (tt & 3) * 16384;
    bf16x8 af[8]; bf16x8 bfr[4];
#pragma unroll
    for (int mf = 0; mf < 8; ++mf)
      af[mf] = *reinterpret_cast<const bf16x8*>(&lds[base + aoff + mf * 128]);
#pragma unroll
    for (int nf = 0; nf < 4; ++nf)
      bfr[nf] = *reinterpret_cast<const bf16x8*>(&lds[base + boff + nf * 128]);
    __builtin_amdgcn_s_setprio(1);
#pragma unroll
    for (int mf = 0; mf < 8; ++mf)
#pragma unroll
      for (int nf = 0; nf < 4; ++nf)
        acc[mf][nf] = __builtin_amdgcn_mfma_f32_16x16x32_bf16(af[mf], bfr[nf], acc[mf][nf], 0, 0, 0);
    __builtin_amdgcn_s_setprio(0);
    asm volatile("" ::: "memory");
  }

  // Epilogue: C/D layout col = lane&15, row = (lane>>4)*4 + r  [m89/m91]
  const int erow = m0 + wm * 128 + (lane >> 4) * 4;
  const int ecol = n0 + wn * 64 + rl;
#pragma unroll
  for (int nf = 0; nf < 4; ++nf) {
    const int col = ecol + nf * 16;
    const float bv = bias[col];
#pragma unroll
    for (int mf = 0; mf < 8; ++mf) {
#pragma unroll
      for (int r = 0; r < 4; ++r) {
        const int row = erow + mf * 16 + r;
        const float z = acc[mf][nf][r] + bv;
        lamh[(size_t)row * D_ + col] = (_Float16)(1.0f / (1.0f + __expf(-z)));
      }
    }
  }
}

// ------------------------------------------------------------- scan pass 1 --
// Per (b, chunk c, 4 d-lanes): local scan with s=0; emit P = prod(lam),
// A = local scan end-state. P/A layout: [c][b*D+d] (transposed for pass2).
__global__ __launch_bounds__(256) void scan_pass1(
    const _Float16* __restrict__ lamh, const float* __restrict__ x,
    float* __restrict__ P, float* __restrict__ Aarr) {
  const int blk = blockIdx.x;
  const int b = blk / CCH, c = blk % CCH;
  const int d4 = threadIdx.x * 4;
  const size_t base = ((size_t)(b * K_ + c * LCH)) * D_ + d4;
  const f16x4*  lp = reinterpret_cast<const f16x4*>(lamh + base);
  const float4* xp = reinterpret_cast<const float4*>(x + base);
  float4 s = {0.f, 0.f, 0.f, 0.f};
  float4 p = {1.f, 1.f, 1.f, 1.f};
#pragma unroll 8
  for (int k = 0; k < LCH; ++k) {
    f16x4  lh = lp[k * (D_ / 4)];
    float4 xv = xp[k * (D_ / 4)];
    float lx = (float)lh.x, ly = (float)lh.y, lz = (float)lh.z, lw = (float)lh.w;
    p.x *= lx; p.y *= ly; p.z *= lz; p.w *= lw;
    s.x = lx * s.x + (1.f - lx) * xv.x;
    s.y = ly * s.y + (1.f - ly) * xv.y;
    s.z = lz * s.z + (1.f - lz) * xv.z;
    s.w = lw * s.w + (1.f - lw) * xv.w;
  }
  const size_t o = (size_t)c * BD_ + b * D_ + d4;
  *reinterpret_cast<float4*>(P + o)    = p;
  *reinterpret_cast<float4*>(Aarr + o) = s;
}

// ------------------------------------------------------------- scan pass 2 --
// Sequential over 512 chunks per (b,d) chain; coalesced rows, 16-deep batches.
__global__ __launch_bounds__(256) void scan_pass2(
    const float* __restrict__ P, const float* __restrict__ Aarr,
    float* __restrict__ S) {
  const int g = blockIdx.x * 256 + threadIdx.x;  // 0..4095 = b*D+d
  float s = 0.f;
  size_t o = g;
  for (int c0 = 0; c0 < CCH; c0 += 16) {
    float p[16], a[16];
#pragma unroll
    for (int j = 0; j < 16; ++j) {
      p[j] = P[o + (size_t)j * BD_];
      a[j] = Aarr[o + (size_t)j * BD_];
    }
    float sv[16];
#pragma unroll
    for (int j = 0; j < 16; ++j) {
      sv[j] = s;
      s = fmaf(p[j], s, a[j]);
    }
#pragma unroll
    for (int j = 0; j < 16; ++j)
      S[o + (size_t)j * BD_] = sv[j];
    o += (size_t)16 * BD_;
  }
}

// ------------------------------------------------------------- scan pass 3 --
// Replay each chunk with correct incoming state, write outputs.
__global__ __launch_bounds__(256) void scan_pass3(
    const _Float16* __restrict__ lamh, const float* __restrict__ x,
    const float* __restrict__ S, float* __restrict__ out) {
  const int blk = blockIdx.x;
  const int b = blk / CCH, c = blk % CCH;
  const int d4 = threadIdx.x * 4;
  float4 s = *reinterpret_cast<const float4*>(S + (size_t)c * BD_ + b * D_ + d4);
  const size_t base = ((size_t)(b * K_ + c * LCH)) * D_ + d4;
  const f16x4*  lp = reinterpret_cast<const f16x4*>(lamh + base);
  const float4* xp = reinterpret_cast<const float4*>(x + base);
  float4* op = reinterpret_cast<float4*>(out + base);
#pragma unroll 8
  for (int k = 0; k < LCH; ++k) {
    f16x4  lh = lp[k * (D_ / 4)];
    float4 xv = xp[k * (D_ / 4)];
    float lx = (float)lh.x, ly = (float)lh.y, lz = (float)lh.z, lw = (float)lh.w;
    s.x = lx * s.x + (1.f - lx) * xv.x;
    s.y = ly * s.y + (1.f - ly) * xv.y;
    s.z = lz * s.z + (1.f - lz) * xv.z;
    s.w = lw * s.w + (1.f - lw) * xv.w;
    op[k * (D_ / 4)] = s;
  }
}

// ------------------------------------------------------------------ launch --
extern "C" void kernel_launch(void* const* d_in, const int* in_sizes, int n_in,
                              void* d_out, int out_size, void* d_ws, size_t ws_size,
                              hipStream_t stream) {
  const float* x    = (const float*)d_in[0];  // [B,K,D]
  const float* W    = (const float*)d_in[1];  // [D,D]
  const float* bias = (const float*)d_in[2];  // [D]
  float* out = (float*)d_out;

  // workspace carve-up (~154 MiB total)
  char* ws = (char*)d_ws;
  unsigned short* xbf = (unsigned short*)ws;                          // 64 MB
  unsigned short* wbf = (unsigned short*)(ws + (size_t)M_ * D_ * 2);  // 2 MB
  _Float16* lamh = (_Float16*)(ws + (size_t)M_ * D_ * 2 + (size_t)D_ * D_ * 2); // 64 MB
  float* P    = (float*)((char*)lamh + (size_t)M_ * D_ * 2);  // 8 MB
  float* Aarr = P   + (size_t)CCH * BD_;    // 8 MB
  float* S    = Aarr + (size_t)CCH * BD_;   // 8 MB

  // allow 128 KiB dynamic LDS for the GEMM (ignore error if already set)
  (void)hipFuncSetAttribute((const void*)gemm_bias_sigmoid,
                            hipFuncAttributeMaxDynamicSharedMemorySize, 131072);

  cvt_f32_to_bf16<<<2048, 256, 0, stream>>>(x, xbf, M_ * D_ / 4);
  cvt_f32_to_bf16<<<512, 256, 0, stream>>>(W, wbf, D_ * D_ / 4);
  gemm_bias_sigmoid<<<512, 512, 131072, stream>>>(xbf, wbf, bias, lamh);
  scan_pass1<<<B_ * CCH, 256, 0, stream>>>(lamh, x, P, Aarr);
  scan_pass2<<<BD_ / 256, 256, 0, stream>>>(P, Aarr, S);  // 16 blocks
  scan_pass3<<<B_ * CCH, 256, 0, stream>>>(lamh, x, S, out);
}